// Round 4
// baseline (7609.716 us; speedup 1.0000x reference)
//
#include <hip/hip_runtime.h>
#include <math.h>

typedef double f64;
#define HDIM 64
#define NNODES 1024
#define NROWS 2048

__device__ __forceinline__ f64 wredsum64(f64 v){
#pragma unroll
  for(int o=32;o>0;o>>=1) v += __shfl_xor(v,o);
  return v;
}

// h1 = (x[:, 0] @ fc_in_w + fc_in_b) @ g_in_w + g_in_b   (one 64-thread block per row)
__global__ void kA_x(const float* __restrict__ x, const float* __restrict__ fw,
                     const float* __restrict__ fb, const float* __restrict__ g_in_w,
                     const float* __restrict__ g_in_b, f64* __restrict__ h1){
  __shared__ f64 lx[64];
  int h = threadIdx.x; int r = blockIdx.x;
  int b = r>>10, n = r&1023;
  const float* xp = x + ((long)(b*32+0)*1024 + n)*6;
  f64 acc = (f64)fb[h];
#pragma unroll
  for(int f=0;f<6;f++) acc += (f64)xp[f] * (f64)fw[f*HDIM+h];
  lx[h] = acc;
  __syncthreads();
  f64 a = (f64)g_in_b[h];
  for(int c=0;c<HDIM;c++) a += lx[c]*(f64)g_in_w[c*HDIM+h];
  h1[(long)r*HDIM+h] = a;
}

// h1 = src @ g_in_w + g_in_b  (f64 src)
__global__ void kA_h(const f64* __restrict__ src, const float* __restrict__ g_in_w,
                     const float* __restrict__ g_in_b, f64* __restrict__ h1){
  __shared__ f64 ls[64];
  int h = threadIdx.x; int r = blockIdx.x;
  ls[h] = src[(long)r*HDIM+h];
  __syncthreads();
  f64 a = (f64)g_in_b[h];
  for(int c=0;c<HDIM;c++) a += ls[c]*(f64)g_in_w[c*HDIM+h];
  h1[(long)r*HDIM+h] = a;
}

// t = h1 @ g_tr_w + g_tr_b ; ss = t.a_src ; sd = t.a_dst  (one wave per row)
__global__ void kB(const f64* __restrict__ h1, const float* __restrict__ g_tr_w,
                   const float* __restrict__ g_tr_b, const float* __restrict__ g_a,
                   f64* __restrict__ ss, f64* __restrict__ sd){
  int h = threadIdx.x; int r = blockIdx.x;
  const f64* row = h1 + (long)r*HDIM;
  f64 t = (f64)g_tr_b[h];
  for(int c=0;c<HDIM;c++) t += row[c]*(f64)g_tr_w[c*HDIM+h];
  f64 s1 = wredsum64(t*(f64)g_a[h]);
  f64 s2 = wredsum64(t*(f64)g_a[HDIM+h]);
  if(h==0){ ss[r]=s1; sd[r]=s2; }
}

// One block (256 thr) per query row i: literal softmax over j (own max), then
// out[i] = att @ h1 + h1[i].
__global__ __launch_bounds__(256) void kC(const f64* __restrict__ h1,
                                          const f64* __restrict__ ss,
                                          const f64* __restrict__ sd,
                                          f64* __restrict__ out){
  __shared__ f64 sc[1024];
  __shared__ f64 red[8];
  __shared__ f64 agg[256];
  int tid = threadIdx.x; int i = blockIdx.x; int b = i>>10;
  const f64* ssb = ss + (long)b*NNODES;
  f64 sdi = sd[i];
  // scores + local max
  f64 lm = -1e300;
  for(int j=tid;j<NNODES;j+=256){
    f64 v = ssb[j] + sdi;
    v = (v >= 0.0) ? v : 0.01*v;     // leaky, literal where-form
    sc[j] = v;
    lm = fmax(lm, v);
  }
#pragma unroll
  for(int o=32;o>0;o>>=1) lm = fmax(lm, __shfl_xor(lm,o));
  if((tid&63)==0) red[tid>>6] = lm;
  __syncthreads();
  f64 m = fmax(fmax(red[0],red[1]), fmax(red[2],red[3]));
  // exp + local sum
  f64 lsum = 0.0;
  for(int j=tid;j<NNODES;j+=256){
    f64 e = exp(sc[j]-m);
    sc[j] = e;
    lsum += e;
  }
  lsum = wredsum64(lsum);
  if((tid&63)==0) red[4+(tid>>6)] = lsum;
  __syncthreads();
  f64 S = red[4]+red[5]+red[6]+red[7];
  // att = exp/sum (literal: divide first, then einsum)
  for(int j=tid;j<NNODES;j+=256) sc[j] = sc[j]/S;
  __syncthreads();
  // aggregate: 4 waves split j-range; deterministic order
  int h = tid&63, part = tid>>6;
  const f64* hb = h1 + (long)b*NNODES*HDIM;
  f64 a = 0.0;
  int j0 = part*256, j1 = j0+256;
  for(int j=j0;j<j1;j++) a += sc[j]*hb[(long)j*HDIM+h];
  agg[tid] = a;
  __syncthreads();
  if(part==0){
    f64 tot = agg[h] + agg[64+h] + agg[128+h] + agg[192+h];
    out[(long)i*HDIM+h] = tot + h1[(long)i*HDIM+h];
  }
}

// GRU: step==0 -> h=gru(gat,0); step>0 -> h=gru(xh[:,:,step], gat). One wave per row.
__global__ void kD(const f64* __restrict__ gat, const float* __restrict__ x,
                   const float* __restrict__ fw, const float* __restrict__ fb,
                   const float* __restrict__ w_ih, const float* __restrict__ w_hh,
                   const float* __restrict__ b_ih, const float* __restrict__ b_hh,
                   f64* __restrict__ hnew, int step){
  __shared__ f64 lin[64];
  __shared__ f64 lh[64];
  int h = threadIdx.x; int r = blockIdx.x;
  int b = r>>10, n = r&1023;
  f64 hv = gat[(long)r*HDIM+h];
  lh[h] = hv;
  if(step>0){
    const float* xp = x + ((long)(b*32+step)*1024 + n)*6;
    f64 xi = (f64)fb[h];
#pragma unroll
    for(int f=0;f<6;f++) xi += (f64)xp[f]*(f64)fw[f*HDIM+h];
    lin[h] = xi;
  } else {
    lin[h] = hv;
  }
  __syncthreads();
  f64 gi0=(f64)b_ih[h], gi1=(f64)b_ih[64+h], gi2=(f64)b_ih[128+h];
  f64 gh0=(f64)b_hh[h], gh1=(f64)b_hh[64+h], gh2=(f64)b_hh[128+h];
  for(int c=0;c<HDIM;c++){
    f64 in = lin[c], ho = lh[c];
    gi0 += in*(f64)w_ih[(0*64+h)*HDIM+c];
    gi1 += in*(f64)w_ih[(64+h)*HDIM+c];
    gi2 += in*(f64)w_ih[(128+h)*HDIM+c];
    if(step>0){
      gh0 += ho*(f64)w_hh[(0*64+h)*HDIM+c];
      gh1 += ho*(f64)w_hh[(64+h)*HDIM+c];
      gh2 += ho*(f64)w_hh[(128+h)*HDIM+c];
    }
  }
  f64 rr = 1.0/(1.0+exp(-(gi0+gh0)));
  f64 zz = 1.0/(1.0+exp(-(gi1+gh1)));
  f64 nn = tanh(gi2 + rr*gh2);
  f64 hn = (step>0) ? ((1.0-zz)*nn + zz*hv) : (1.0-zz)*nn;
  hnew[(long)r*HDIM+h] = hn;
}

// FFN head: out[r] = leaky(h@ffn_w+ffn_b) @ ffn_ow + ffn_ob  -> f32
__global__ void kE(const f64* __restrict__ hf, const float* __restrict__ ffn_w,
                   const float* __restrict__ ffn_b, const float* __restrict__ ffn_ow,
                   const float* __restrict__ ffn_ob, float* __restrict__ out){
  __shared__ f64 ls[64];
  int h = threadIdx.x; int r = blockIdx.x;
  ls[h] = hf[(long)r*HDIM+h];
  __syncthreads();
  f64 a = (f64)ffn_b[h];
  for(int c=0;c<HDIM;c++) a += ls[c]*(f64)ffn_w[c*HDIM+h];
  a = (a >= 0.0) ? a : 0.01*a;
  f64 p = wredsum64(a*(f64)ffn_ow[h]);
  if(h==0) out[r] = (float)(p + (f64)ffn_ob[0]);
}

extern "C" void kernel_launch(void* const* d_in, const int* in_sizes, int n_in,
                              void* d_out, int out_size, void* d_ws, size_t ws_size,
                              hipStream_t stream){
  const float* x      = (const float*)d_in[0];
  const float* fc_in_w= (const float*)d_in[1];
  const float* fc_in_b= (const float*)d_in[2];
  const float* g_in_w = (const float*)d_in[3];
  const float* g_in_b = (const float*)d_in[4];
  const float* g_tr_w = (const float*)d_in[5];
  const float* g_tr_b = (const float*)d_in[6];
  const float* g_a    = (const float*)d_in[7];
  const float* w_ih   = (const float*)d_in[8];
  const float* w_hh   = (const float*)d_in[9];
  const float* b_ih   = (const float*)d_in[10];
  const float* b_hh   = (const float*)d_in[11];
  const float* ffn_w  = (const float*)d_in[12];
  const float* ffn_b  = (const float*)d_in[13];
  const float* ffn_ow = (const float*)d_in[14];
  const float* ffn_ob = (const float*)d_in[15];

  // workspace (f64): 2*131072 + 2*2048 doubles = 2.13 MB
  f64* h1a = (f64*)d_ws;
  f64* h1b = h1a + (long)NROWS*HDIM;
  f64* ss  = h1b + (long)NROWS*HDIM;
  f64* sd  = ss + NROWS;

  float* dout = (float*)d_out;

  kA_x<<<NROWS,64,0,stream>>>(x, fc_in_w, fc_in_b, g_in_w, g_in_b, h1a);

  for(int s=0;s<31;s++){
    // GAT iter 1: scores from h1a, agg -> h1b
    kB<<<NROWS,64,0,stream>>>(h1a, g_tr_w, g_tr_b, g_a, ss, sd);
    kC<<<NROWS,256,0,stream>>>(h1a, ss, sd, h1b);
    // GAT iter 2: scores from h1b, agg -> h1a (gat output)
    kB<<<NROWS,64,0,stream>>>(h1b, g_tr_w, g_tr_b, g_a, ss, sd);
    kC<<<NROWS,256,0,stream>>>(h1b, ss, sd, h1a);
    // GRU -> h1b (hnew)
    kD<<<NROWS,64,0,stream>>>(h1a, x, fc_in_w, fc_in_b, w_ih, w_hh, b_ih, b_hh, h1b, s);
    if(s<30){
      // next h1 = hnew @ g_in_w + b -> h1a
      kA_h<<<NROWS,64,0,stream>>>(h1b, g_in_w, g_in_b, h1a);
    } else {
      kE<<<NROWS,64,0,stream>>>(h1b, ffn_w, ffn_b, ffn_ow, ffn_ob, dout);
    }
  }
}

// Round 5
// 3161.466 us; speedup vs baseline: 2.4070x; 2.4070x over previous
//
#include <hip/hip_runtime.h>
#include <math.h>

typedef double f64;
#define HDIM 64
#define NNODES 1024
#define NROWS 2048

__device__ __forceinline__ f64 wredsum64(f64 v){
#pragma unroll
  for(int o=32;o>0;o>>=1) v += __shfl_xor(v,o);
  return v;
}

// Two-stage score, identical op/order to the passing kB:
// t[h] = g_tr_b[h] + sum_c row[c]*g_tr_w[c,h]; s = butterfly-sum(t*a)
__device__ __forceinline__ void s_twostage64(const f64* __restrict__ ldsrow,
    const float* __restrict__ g_tr_w, const float* __restrict__ g_tr_b,
    const float* __restrict__ g_a, int h, f64& s_src, f64& s_dst){
  f64 t = (f64)g_tr_b[h];
  for(int c=0;c<HDIM;c++) t = fma(ldsrow[c], (f64)g_tr_w[c*HDIM+h], t);
  s_src = wredsum64(t*(f64)g_a[h]);
  s_dst = wredsum64(t*(f64)g_a[HDIM+h]);
}

// Transpose GRU weights to f64 for coalesced reads. 1 block x 64 threads.
__global__ void k_pre(const float* __restrict__ w_ih, const float* __restrict__ w_hh,
                      f64* w_ihT, f64* w_hhT){
  int t = threadIdx.x;
  for(int k=t;k<192*HDIM;k+=64){
    int row=k/HDIM, c=k%HDIM;
    w_ihT[c*192+row]=(f64)w_ih[k];
    w_hhT[c*192+row]=(f64)w_hh[k];
  }
}

// h1_0 = (x[:,0]@fc_in_w+fc_in_b) @ g_in_w + g_in_b ; + two-stage s. 1 wave/row.
__global__ void k1(const float* __restrict__ x, const float* __restrict__ fw,
                   const float* __restrict__ fb,
                   const float* __restrict__ g_in_w, const float* __restrict__ g_in_b,
                   const float* __restrict__ g_tr_w, const float* __restrict__ g_tr_b,
                   const float* __restrict__ g_a,
                   f64* __restrict__ h1, f64* __restrict__ ssrc, f64* __restrict__ sdst){
  __shared__ f64 lx[4*64];
  __shared__ f64 lt[4*64];
  int wave = threadIdx.x >> 6, h = threadIdx.x & 63;
  int r = blockIdx.x*4 + wave;
  int b = r >> 10, n = r & 1023;
  const float* xp = x + ((long)(b*32 + 0)*1024 + n)*6;
  f64 xh = (f64)fb[h];
#pragma unroll
  for(int f=0;f<6;f++) xh += (f64)xp[f]*(f64)fw[f*HDIM+h];
  lx[wave*64+h] = xh;
  __syncthreads();
  f64 a = (f64)g_in_b[h];
  for(int c=0;c<HDIM;c++) a += lx[wave*64+c]*(f64)g_in_w[c*HDIM+h];
  h1[(long)r*HDIM+h] = a;
  lt[wave*64+h] = a;
  __syncthreads();
  f64 s1,s2;
  s_twostage64(lt+wave*64, g_tr_w,g_tr_b,g_a, h, s1,s2);
  if(h==0){ ssrc[r]=s1; sdst[r]=s2; }
}

// Fused attention step, all-f64. 256 blocks x 256 threads, 8 rows/block.
// M=0: h1_out = agg + residual, + scores of result.
// M=1: agg -> gat out; fused GRU; then next-step h1 + scores (is_final==0)
//      or FFN head -> d_out (is_final==1).
template<int M>
__global__ __launch_bounds__(256) void k_att(
    const f64* __restrict__ h1_in, const f64* __restrict__ ssrc_in,
    const f64* __restrict__ sdst_in,
    f64* __restrict__ h1_out, f64* __restrict__ ssrc_out, f64* __restrict__ sdst_out,
    const float* __restrict__ g_tr_w, const float* __restrict__ g_tr_b,
    const float* __restrict__ g_a,
    const float* __restrict__ x, const float* __restrict__ fw, const float* __restrict__ fb,
    const f64* __restrict__ w_ihT, const f64* __restrict__ w_hhT,
    const float* __restrict__ b_ih, const float* __restrict__ b_hh,
    const float* __restrict__ g_in_w, const float* __restrict__ g_in_b,
    const float* __restrict__ ffn_w, const float* __restrict__ ffn_b,
    const float* __restrict__ ffn_ow, const float* __restrict__ ffn_ob,
    float* __restrict__ out, int step, int is_final)
{
  __shared__ __align__(16) f64 lds_h1[64*64]; // 32 KB j-tile (reused for h_new rows in M=1)
  __shared__ __align__(16) f64 lds_w[8*64];   // softmax weights (reused for out rows)
  __shared__ __align__(16) f64 lds_x[8*64];   // GRU input rows / next-h1 rows
  __shared__ f64 lds_sd[8];
  __shared__ f64 lds_m[8];
  __shared__ f64 lds_red[4];

  const int tid = threadIdx.x;
  const int wave = tid>>6, h = tid&63;
  const int batch = blockIdx.x>>7;
  const int r0 = (blockIdx.x&127)*8;
  const long gr0 = (long)batch*NNODES + r0;

  // per-batch max of s_src; row max = leaky(maxS + sd_i) exactly (monotone)
  const f64* sb = ssrc_in + (long)batch*NNODES;
  f64 mx = -1e300;
  for(int j=tid;j<NNODES;j+=256) mx = fmax(mx, sb[j]);
#pragma unroll
  for(int o=32;o>0;o>>=1) mx = fmax(mx, __shfl_xor(mx,o));
  if(h==0) lds_red[wave]=mx;
  __syncthreads();
  f64 maxS = fmax(fmax(lds_red[0],lds_red[1]),fmax(lds_red[2],lds_red[3]));
  if(tid<8){
    f64 sd = sdst_in[gr0+tid];
    lds_sd[tid]=sd;
    f64 v = maxS + sd;
    lds_m[tid] = (v>=0.0)? v : 0.01*v;
  }
  __syncthreads();

  const int yA = wave*2, yB = wave*2+1;
  f64 accA=0.0, accB=0.0, wsA=0.0, wsB=0.0;

  for(int jt=0;jt<16;jt++){
    const int j0 = jt*64;
    const f64* src = h1_in + ((long)batch*NNODES + j0)*HDIM;
#pragma unroll
    for(int k=0;k<8;k++){
      int idx = tid + k*256;   // 2048 double2 slots
      ((double2*)lds_h1)[idx] = ((const double2*)src)[idx];
    }
#pragma unroll
    for(int k=0;k<2;k++){
      int idx = tid + k*256;
      int row = idx>>6, jj = idx&63;
      f64 v = sb[j0+jj] + lds_sd[row];
      v = (v>=0.0)? v : 0.01*v;
      lds_w[idx] = exp(v - lds_m[row]);
    }
    __syncthreads();
#pragma unroll 4
    for(int q=0;q<16;q++){
      const f64* wA = lds_w + yA*64 + q*4;
      const f64* wB = lds_w + yB*64 + q*4;
      double2 wa01 = *(const double2*)(wA);
      double2 wa23 = *(const double2*)(wA+2);
      double2 wb01 = *(const double2*)(wB);
      double2 wb23 = *(const double2*)(wB+2);
      int base = q*4*64 + h;
      f64 h0 = lds_h1[base], h1v = lds_h1[base+64];
      f64 h2 = lds_h1[base+128], h3 = lds_h1[base+192];
      accA = fma(wa01.x,h0,accA); accA = fma(wa01.y,h1v,accA);
      accA = fma(wa23.x,h2,accA); accA = fma(wa23.y,h3,accA);
      accB = fma(wb01.x,h0,accB); accB = fma(wb01.y,h1v,accB);
      accB = fma(wb23.x,h2,accB); accB = fma(wb23.y,h3,accB);
      wsA += (wa01.x+wa01.y)+(wa23.x+wa23.y);
      wsB += (wb01.x+wb01.y)+(wb23.x+wb23.y);
    }
    __syncthreads();
  }

  const long grA = gr0 + yA, grB = gr0 + yB;
  f64 outA = accA/wsA + h1_in[grA*HDIM + h];
  f64 outB = accB/wsB + h1_in[grB*HDIM + h];

  if(M==0){
    h1_out[grA*HDIM+h]=outA; h1_out[grB*HDIM+h]=outB;
    lds_w[yA*64+h]=outA; lds_w[yB*64+h]=outB;
    __syncthreads();
    f64 sA1,sA2,sB1,sB2;
    s_twostage64(lds_w+yA*64, g_tr_w,g_tr_b,g_a, h, sA1,sA2);
    s_twostage64(lds_w+yB*64, g_tr_w,g_tr_b,g_a, h, sB1,sB2);
    if(h==0){
      ssrc_out[grA]=sA1; sdst_out[grA]=sA2;
      ssrc_out[grB]=sB1; sdst_out[grB]=sB2;
    }
    return;
  } else {
    lds_w[yA*64+h]=outA; lds_w[yB*64+h]=outB;
    const bool hasxi = (step > 0);
    if(hasxi){
      const int nA = r0+yA, nB = r0+yB;
      const float* xpA = x + ((long)(batch*32 + step)*1024 + nA)*6;
      const float* xpB = x + ((long)(batch*32 + step)*1024 + nB)*6;
      f64 xa = (f64)fb[h], xb = (f64)fb[h];
#pragma unroll
      for(int f=0;f<6;f++){
        xa += (f64)xpA[f]*(f64)fw[f*HDIM+h];
        xb += (f64)xpB[f]*(f64)fw[f*HDIM+h];
      }
      lds_x[yA*64+h]=xa; lds_x[yB*64+h]=xb;
    }
    __syncthreads();
    // ---- fused GRU (same c-order as the passing kD) ----
    f64 gi0A=(f64)b_ih[h], gi1A=(f64)b_ih[64+h], gi2A=(f64)b_ih[128+h];
    f64 gi0B=gi0A, gi1B=gi1A, gi2B=gi2A;
    f64 gh0A=(f64)b_hh[h], gh1A=(f64)b_hh[64+h], gh2A=(f64)b_hh[128+h];
    f64 gh0B=gh0A, gh1B=gh1A, gh2B=gh2A;
    for(int c=0;c<HDIM;c++){
      f64 wi0 = w_ihT[c*192 + h], wi1 = w_ihT[c*192 + 64 + h], wi2 = w_ihT[c*192 + 128 + h];
      f64 oA = lds_w[yA*64+c], oB = lds_w[yB*64+c];
      f64 inA = hasxi ? lds_x[yA*64+c] : oA;
      f64 inB = hasxi ? lds_x[yB*64+c] : oB;
      gi0A += inA*wi0; gi1A += inA*wi1; gi2A += inA*wi2;
      gi0B += inB*wi0; gi1B += inB*wi1; gi2B += inB*wi2;
      if(hasxi){
        f64 wh0 = w_hhT[c*192 + h], wh1 = w_hhT[c*192 + 64 + h], wh2 = w_hhT[c*192 + 128 + h];
        gh0A += oA*wh0; gh1A += oA*wh1; gh2A += oA*wh2;
        gh0B += oB*wh0; gh1B += oB*wh1; gh2B += oB*wh2;
      }
    }
    f64 rA = 1.0/(1.0+exp(-(gi0A+gh0A))), zA = 1.0/(1.0+exp(-(gi1A+gh1A)));
    f64 nA_ = tanh(gi2A + rA*gh2A);
    f64 rB = 1.0/(1.0+exp(-(gi0B+gh0B))), zB = 1.0/(1.0+exp(-(gi1B+gh1B)));
    f64 nB_ = tanh(gi2B + rB*gh2B);
    f64 hnA = hasxi ? ((1.0-zA)*nA_ + zA*outA) : (1.0-zA)*nA_;
    f64 hnB = hasxi ? ((1.0-zB)*nB_ + zB*outB) : (1.0-zB)*nB_;
    lds_h1[yA*64+h]=hnA; lds_h1[yB*64+h]=hnB;
    __syncthreads();
    if(!is_final){
      // next h1 = h_new @ g_in_w + b (same c-order as kA_h), + scores
      f64 a1A = (f64)g_in_b[h], a1B = a1A;
      for(int c=0;c<HDIM;c++){
        f64 w = (f64)g_in_w[c*HDIM+h];
        a1A += lds_h1[yA*64+c]*w;
        a1B += lds_h1[yB*64+c]*w;
      }
      h1_out[grA*HDIM+h]=a1A; h1_out[grB*HDIM+h]=a1B;
      lds_x[yA*64+h]=a1A; lds_x[yB*64+h]=a1B;
      __syncthreads();
      f64 sA1,sA2,sB1,sB2;
      s_twostage64(lds_x+yA*64, g_tr_w,g_tr_b,g_a, h, sA1,sA2);
      s_twostage64(lds_x+yB*64, g_tr_w,g_tr_b,g_a, h, sB1,sB2);
      if(h==0){
        ssrc_out[grA]=sA1; sdst_out[grA]=sA2;
        ssrc_out[grB]=sB1; sdst_out[grB]=sB2;
      }
    } else {
      // FFN head (same order as kE)
      f64 hidA = (f64)ffn_b[h], hidB = hidA;
      for(int c=0;c<HDIM;c++){
        f64 w = (f64)ffn_w[c*HDIM+h];
        hidA += lds_h1[yA*64+c]*w;
        hidB += lds_h1[yB*64+c]*w;
      }
      hidA = (hidA>=0.0)? hidA : 0.01*hidA;
      hidB = (hidB>=0.0)? hidB : 0.01*hidB;
      f64 oA2 = wredsum64(hidA*(f64)ffn_ow[h]);
      f64 oB2 = wredsum64(hidB*(f64)ffn_ow[h]);
      if(h==0){
        out[grA] = (float)(oA2 + (f64)ffn_ob[0]);
        out[grB] = (float)(oB2 + (f64)ffn_ob[0]);
      }
    }
  }
}

extern "C" void kernel_launch(void* const* d_in, const int* in_sizes, int n_in,
                              void* d_out, int out_size, void* d_ws, size_t ws_size,
                              hipStream_t stream){
  const float* x      = (const float*)d_in[0];
  const float* fc_in_w= (const float*)d_in[1];
  const float* fc_in_b= (const float*)d_in[2];
  const float* g_in_w = (const float*)d_in[3];
  const float* g_in_b = (const float*)d_in[4];
  const float* g_tr_w = (const float*)d_in[5];
  const float* g_tr_b = (const float*)d_in[6];
  const float* g_a    = (const float*)d_in[7];
  const float* w_ih   = (const float*)d_in[8];
  const float* w_hh   = (const float*)d_in[9];
  const float* b_ih   = (const float*)d_in[10];
  const float* b_hh   = (const float*)d_in[11];
  const float* ffn_w  = (const float*)d_in[12];
  const float* ffn_b  = (const float*)d_in[13];
  const float* ffn_ow = (const float*)d_in[14];
  const float* ffn_ob = (const float*)d_in[15];

  // workspace (f64): 2*131072 + 4*2048 + 2*12288 doubles ≈ 2.26 MB
  f64* h1a   = (f64*)d_ws;
  f64* h1b   = h1a + (long)NROWS*HDIM;
  f64* ssa   = h1b + (long)NROWS*HDIM;
  f64* sda   = ssa + NROWS;
  f64* ssb   = sda + NROWS;
  f64* sdb   = ssb + NROWS;
  f64* w_ihT = sdb + NROWS;
  f64* w_hhT = w_ihT + 192*HDIM;

  float* dout = (float*)d_out;

  k_pre<<<1,64,0,stream>>>(w_ih,w_hh,w_ihT,w_hhT);
  k1<<<NROWS/4,256,0,stream>>>(x, fc_in_w, fc_in_b, g_in_w,g_in_b,
                               g_tr_w,g_tr_b,g_a, h1a,ssa,sda);

  for(int s=0;s<31;s++){
    k_att<0><<<256,256,0,stream>>>(h1a,ssa,sda, h1b,ssb,sdb,
                                   g_tr_w,g_tr_b,g_a,
                                   x,fc_in_w,fc_in_b,
                                   w_ihT,w_hhT,b_ih,b_hh,
                                   g_in_w,g_in_b,
                                   ffn_w,ffn_b,ffn_ow,ffn_ob,
                                   dout, s, 0);
    k_att<1><<<256,256,0,stream>>>(h1b,ssb,sdb, h1a,ssa,sda,
                                   g_tr_w,g_tr_b,g_a,
                                   x,fc_in_w,fc_in_b,
                                   w_ihT,w_hhT,b_ih,b_hh,
                                   g_in_w,g_in_b,
                                   ffn_w,ffn_b,ffn_ow,ffn_ob,
                                   dout, s, (s==30)?1:0);
  }
}

// Round 6
// 2533.657 us; speedup vs baseline: 3.0035x; 1.2478x over previous
//
#include <hip/hip_runtime.h>
#include <math.h>

typedef double f64;
#define HDIM 64
#define NNODES 1024
#define NROWS 2048
#define RPB 16      // rows per kAgg block
#define NCH 4       // j-chunks
#define CHJ (NNODES/NCH)   // 256 j per chunk

__device__ __forceinline__ f64 wredsum64(f64 v){
#pragma unroll
  for(int o=32;o>0;o>>=1) v += __shfl_xor(v,o);
  return v;
}

// two-stage score, same op-order as the absmax-0 version
__device__ __forceinline__ void s_twostage64(const f64* __restrict__ ldsrow,
    const float* __restrict__ g_tr_w, const float* __restrict__ g_tr_b,
    const float* __restrict__ g_a, int h, f64& s_src, f64& s_dst){
  f64 t = (f64)g_tr_b[h];
  for(int c=0;c<HDIM;c++) t = fma(ldsrow[c], (f64)g_tr_w[c*HDIM+h], t);
  s_src = wredsum64(t*(f64)g_a[h]);
  s_dst = wredsum64(t*(f64)g_a[HDIM+h]);
}

// parallel f64 transpose of GRU weights: 48 blocks x 256
__global__ void k_pre(const float* __restrict__ w_ih, const float* __restrict__ w_hh,
                      f64* __restrict__ w_ihT, f64* __restrict__ w_hhT){
  int k = blockIdx.x*256 + threadIdx.x;
  if(k >= 192*HDIM) return;
  int row=k>>6, c=k&63;
  w_ihT[c*192+row]=(f64)w_ih[k];
  w_hhT[c*192+row]=(f64)w_hh[k];
}

// initial h1 + scores. 1 wave/row.
__global__ void k1(const float* __restrict__ x, const float* __restrict__ fw,
                   const float* __restrict__ fb,
                   const float* __restrict__ g_in_w, const float* __restrict__ g_in_b,
                   const float* __restrict__ g_tr_w, const float* __restrict__ g_tr_b,
                   const float* __restrict__ g_a,
                   f64* __restrict__ h1, f64* __restrict__ ssrc, f64* __restrict__ sdst){
  __shared__ f64 lx[4*64];
  __shared__ f64 lt[4*64];
  int wave = threadIdx.x >> 6, h = threadIdx.x & 63;
  int r = blockIdx.x*4 + wave;
  int b = r >> 10, n = r & 1023;
  const float* xp = x + ((long)(b*32 + 0)*1024 + n)*6;
  f64 xh = (f64)fb[h];
#pragma unroll
  for(int f=0;f<6;f++) xh += (f64)xp[f]*(f64)fw[f*HDIM+h];
  lx[wave*64+h] = xh;
  __syncthreads();
  f64 a = (f64)g_in_b[h];
  for(int c=0;c<HDIM;c++) a += lx[wave*64+c]*(f64)g_in_w[c*HDIM+h];
  h1[(long)r*HDIM+h] = a;
  lt[wave*64+h] = a;
  __syncthreads();
  f64 s1,s2;
  s_twostage64(lt+wave*64, g_tr_w,g_tr_b,g_a, h, s1,s2);
  if(h==0){ ssrc[r]=s1; sdst[r]=s2; }
}

// Partial attention aggregation. grid = (NROWS/RPB)*NCH = 512 blocks x 256 thr.
// Block (rg, chunk): rows rg*16..+15, j in [chunk*256, chunk*256+256).
// Writes pacc[chunk][row][h], pws[chunk][row].
__global__ __launch_bounds__(256) void kAgg(
    const f64* __restrict__ h1_in, const f64* __restrict__ ss_in,
    const f64* __restrict__ sd_in,
    f64* __restrict__ pacc, f64* __restrict__ pws)
{
  __shared__ __align__(16) f64 htile[64*64];  // 32 KB
  __shared__ __align__(16) f64 wbuf[RPB*64];  // 8 KB
  __shared__ f64 lds_m[RPB];
  __shared__ f64 lds_sd[RPB];
  __shared__ f64 red[4];

  const int tid = threadIdx.x, wave = tid>>6, h = tid&63;
  const int chunk = blockIdx.x & (NCH-1);
  const int rg = blockIdx.x >> 2;           // 0..127
  const int batch = rg >> 6;                // 16 rows * 64 rgs = 1024 rows/batch
  const int r0 = rg*RPB;                    // global row base (0..2047)

  const f64* sb = ss_in + (long)batch*NNODES;
  // batch max of s_src
  f64 mx = -1e300;
  for(int j=tid;j<NNODES;j+=256) mx = fmax(mx, sb[j]);
#pragma unroll
  for(int o=32;o>0;o>>=1) mx = fmax(mx, __shfl_xor(mx,o));
  if(h==0) red[wave]=mx;
  __syncthreads();
  f64 maxS = fmax(fmax(red[0],red[1]),fmax(red[2],red[3]));
  if(tid<RPB){
    f64 sd = sd_in[r0+tid];
    lds_sd[tid]=sd;
    f64 v = maxS + sd;
    lds_m[tid] = (v>=0.0)? v : 0.01*v;
  }
  __syncthreads();

  f64 acc0=0.0, acc1=0.0, acc2=0.0, acc3=0.0;   // rows wave*4+0..3
  f64 wsk0=0.0, wsk1=0.0, wsk2=0.0, wsk3=0.0;   // ws rows k*4+wave, k=0..3

  for(int st=0; st<CHJ/64; st++){
    const int j0 = chunk*CHJ + st*64;
    const f64* src = h1_in + ((long)batch*NNODES + j0)*HDIM;
#pragma unroll
    for(int k=0;k<8;k++){
      int idx = tid + k*256;
      ((double2*)htile)[idx] = ((const double2*)src)[idx];
    }
    // W rows: iteration k covers row k*4+wave (lanes = 64 j values)
#pragma unroll
    for(int k=0;k<4;k++){
      int row = k*4 + wave;
      f64 v = sb[j0+h] + lds_sd[row];
      v = (v>=0.0)? v : 0.01*v;
      f64 e = exp(v - lds_m[row]);
      wbuf[row*64+h] = e;
      f64 s = wredsum64(e);
      if(k==0) wsk0+=s; else if(k==1) wsk1+=s; else if(k==2) wsk2+=s; else wsk3+=s;
    }
    __syncthreads();
    const f64* wb = wbuf + (wave*4)*64;
#pragma unroll 4
    for(int jg=0; jg<16; jg++){
      int base = jg*4*64 + h;
      f64 h0 = htile[base], h1v = htile[base+64];
      f64 h2 = htile[base+128], h3 = htile[base+192];
      double2 wa = *(const double2*)(wb + jg*4);
      double2 wa2= *(const double2*)(wb + jg*4 + 2);
      double2 wbv= *(const double2*)(wb + 64 + jg*4);
      double2 wb2= *(const double2*)(wb + 64 + jg*4 + 2);
      double2 wc = *(const double2*)(wb + 128 + jg*4);
      double2 wc2= *(const double2*)(wb + 128 + jg*4 + 2);
      double2 wd = *(const double2*)(wb + 192 + jg*4);
      double2 wd2= *(const double2*)(wb + 192 + jg*4 + 2);
      acc0 = fma(wa.x,h0,acc0);  acc0 = fma(wa.y,h1v,acc0);
      acc0 = fma(wa2.x,h2,acc0); acc0 = fma(wa2.y,h3,acc0);
      acc1 = fma(wbv.x,h0,acc1); acc1 = fma(wbv.y,h1v,acc1);
      acc1 = fma(wb2.x,h2,acc1); acc1 = fma(wb2.y,h3,acc1);
      acc2 = fma(wc.x,h0,acc2);  acc2 = fma(wc.y,h1v,acc2);
      acc2 = fma(wc2.x,h2,acc2); acc2 = fma(wc2.y,h3,acc2);
      acc3 = fma(wd.x,h0,acc3);  acc3 = fma(wd.y,h1v,acc3);
      acc3 = fma(wd2.x,h2,acc3); acc3 = fma(wd2.y,h3,acc3);
    }
    __syncthreads();
  }

  const long pbase = ((long)chunk*NROWS + r0)*HDIM;
  pacc[pbase + (wave*4+0)*HDIM + h] = acc0;
  pacc[pbase + (wave*4+1)*HDIM + h] = acc1;
  pacc[pbase + (wave*4+2)*HDIM + h] = acc2;
  pacc[pbase + (wave*4+3)*HDIM + h] = acc3;
  if(h==0){
    f64* pw = pws + (long)chunk*NROWS + r0;
    pw[0*4+wave] = wsk0; pw[1*4+wave] = wsk1;
    pw[2*4+wave] = wsk2; pw[3*4+wave] = wsk3;
  }
}

// Combine partials -> gat-iter output + residual; then scores. 1 wave/row, grid 512.
__global__ void kFin0(const f64* __restrict__ pacc, const f64* __restrict__ pws,
                      const f64* __restrict__ h1_in,
                      const float* __restrict__ g_tr_w, const float* __restrict__ g_tr_b,
                      const float* __restrict__ g_a,
                      f64* __restrict__ h1_out, f64* __restrict__ ss_out, f64* __restrict__ sd_out){
  __shared__ f64 lt[4*64];
  int wave = threadIdx.x>>6, h = threadIdx.x&63;
  long r = blockIdx.x*4 + wave;
  f64 a = 0.0, w = 0.0;
#pragma unroll
  for(int c=0;c<NCH;c++){
    a += pacc[((long)c*NROWS + r)*HDIM + h];
    w += pws[(long)c*NROWS + r];
  }
  f64 out = a/w + h1_in[r*HDIM+h];
  h1_out[r*HDIM+h] = out;
  lt[wave*64+h] = out;
  __syncthreads();
  f64 s1,s2;
  s_twostage64(lt+wave*64, g_tr_w,g_tr_b,g_a, h, s1,s2);
  if(h==0){ ss_out[r]=s1; sd_out[r]=s2; }
}

// Combine -> gat out; GRU; then next h1+scores or FFN head. 1 wave/row, grid 512.
__global__ void kFin1(const f64* __restrict__ pacc, const f64* __restrict__ pws,
                      const f64* __restrict__ h1_in,
                      const float* __restrict__ x, const float* __restrict__ fw,
                      const float* __restrict__ fb,
                      const f64* __restrict__ w_ihT, const f64* __restrict__ w_hhT,
                      const float* __restrict__ b_ih, const float* __restrict__ b_hh,
                      const float* __restrict__ g_in_w, const float* __restrict__ g_in_b,
                      const float* __restrict__ g_tr_w, const float* __restrict__ g_tr_b,
                      const float* __restrict__ g_a,
                      const float* __restrict__ ffn_w, const float* __restrict__ ffn_b,
                      const float* __restrict__ ffn_ow, const float* __restrict__ ffn_ob,
                      f64* __restrict__ h1_out, f64* __restrict__ ss_out, f64* __restrict__ sd_out,
                      float* __restrict__ out, int step, int is_final){
  __shared__ f64 lo[4*64];
  __shared__ f64 lx[4*64];
  __shared__ f64 lh[4*64];
  int wave = threadIdx.x>>6, h = threadIdx.x&63;
  long r = blockIdx.x*4 + wave;
  int batch = (int)(r>>10), n = (int)(r&1023);
  f64 a = 0.0, w = 0.0;
#pragma unroll
  for(int c=0;c<NCH;c++){
    a += pacc[((long)c*NROWS + r)*HDIM + h];
    w += pws[(long)c*NROWS + r];
  }
  f64 gato = a/w + h1_in[r*HDIM+h];
  lo[wave*64+h] = gato;
  const bool hasxi = (step>0);
  if(hasxi){
    const float* xp = x + ((long)(batch*32 + step)*1024 + n)*6;
    f64 xi = (f64)fb[h];
#pragma unroll
    for(int f=0;f<6;f++) xi += (f64)xp[f]*(f64)fw[f*HDIM+h];
    lx[wave*64+h] = xi;
  }
  __syncthreads();
  f64 gi0=(f64)b_ih[h], gi1=(f64)b_ih[64+h], gi2=(f64)b_ih[128+h];
  f64 gh0=(f64)b_hh[h], gh1=(f64)b_hh[64+h], gh2=(f64)b_hh[128+h];
  for(int c=0;c<HDIM;c++){
    f64 o = lo[wave*64+c];
    f64 in = hasxi ? lx[wave*64+c] : o;
    gi0 += in*w_ihT[c*192+h]; gi1 += in*w_ihT[c*192+64+h]; gi2 += in*w_ihT[c*192+128+h];
    if(hasxi){
      gh0 += o*w_hhT[c*192+h]; gh1 += o*w_hhT[c*192+64+h]; gh2 += o*w_hhT[c*192+128+h];
    }
  }
  f64 rr = 1.0/(1.0+exp(-(gi0+gh0)));
  f64 zz = 1.0/(1.0+exp(-(gi1+gh1)));
  f64 nn = tanh(gi2 + rr*gh2);
  f64 hn = hasxi ? ((1.0-zz)*nn + zz*gato) : (1.0-zz)*nn;
  lh[wave*64+h] = hn;
  __syncthreads();
  if(!is_final){
    f64 a1 = (f64)g_in_b[h];
    for(int c=0;c<HDIM;c++) a1 += lh[wave*64+c]*(f64)g_in_w[c*HDIM+h];
    h1_out[r*HDIM+h] = a1;
    lx[wave*64+h] = a1;
    __syncthreads();
    f64 s1,s2;
    s_twostage64(lx+wave*64, g_tr_w,g_tr_b,g_a, h, s1,s2);
    if(h==0){ ss_out[r]=s1; sd_out[r]=s2; }
  } else {
    f64 hid = (f64)ffn_b[h];
    for(int c=0;c<HDIM;c++) hid += lh[wave*64+c]*(f64)ffn_w[c*HDIM+h];
    hid = (hid>=0.0)? hid : 0.01*hid;
    f64 o2 = wredsum64(hid*(f64)ffn_ow[h]);
    if(h==0) out[r] = (float)(o2 + (f64)ffn_ob[0]);
  }
}

extern "C" void kernel_launch(void* const* d_in, const int* in_sizes, int n_in,
                              void* d_out, int out_size, void* d_ws, size_t ws_size,
                              hipStream_t stream){
  const float* x      = (const float*)d_in[0];
  const float* fc_in_w= (const float*)d_in[1];
  const float* fc_in_b= (const float*)d_in[2];
  const float* g_in_w = (const float*)d_in[3];
  const float* g_in_b = (const float*)d_in[4];
  const float* g_tr_w = (const float*)d_in[5];
  const float* g_tr_b = (const float*)d_in[6];
  const float* g_a    = (const float*)d_in[7];
  const float* w_ih   = (const float*)d_in[8];
  const float* w_hh   = (const float*)d_in[9];
  const float* b_ih   = (const float*)d_in[10];
  const float* b_hh   = (const float*)d_in[11];
  const float* ffn_w  = (const float*)d_in[12];
  const float* ffn_b  = (const float*)d_in[13];
  const float* ffn_ow = (const float*)d_in[14];
  const float* ffn_ob = (const float*)d_in[15];

  // workspace (f64): h1a,h1b 2*131072; scores 4*2048; wT 2*12288; pacc 524288; pws 8192  ~6.6MB
  f64* h1a   = (f64*)d_ws;
  f64* h1b   = h1a + (long)NROWS*HDIM;
  f64* ssa   = h1b + (long)NROWS*HDIM;
  f64* sda   = ssa + NROWS;
  f64* ssb   = sda + NROWS;
  f64* sdb   = ssb + NROWS;
  f64* w_ihT = sdb + NROWS;
  f64* w_hhT = w_ihT + 192*HDIM;
  f64* pacc  = w_hhT + 192*HDIM;
  f64* pws   = pacc + (long)NCH*NROWS*HDIM;

  float* dout = (float*)d_out;

  k_pre<<<48,256,0,stream>>>(w_ih,w_hh,w_ihT,w_hhT);
  k1<<<NROWS/4,256,0,stream>>>(x, fc_in_w, fc_in_b, g_in_w,g_in_b,
                               g_tr_w,g_tr_b,g_a, h1a,ssa,sda);

  for(int s=0;s<31;s++){
    kAgg<<<(NROWS/RPB)*NCH,256,0,stream>>>(h1a,ssa,sda, pacc,pws);
    kFin0<<<NROWS/4,256,0,stream>>>(pacc,pws,h1a, g_tr_w,g_tr_b,g_a, h1b,ssb,sdb);
    kAgg<<<(NROWS/RPB)*NCH,256,0,stream>>>(h1b,ssb,sdb, pacc,pws);
    kFin1<<<NROWS/4,256,0,stream>>>(pacc,pws,h1b,
                                    x,fc_in_w,fc_in_b,
                                    w_ihT,w_hhT,b_ih,b_hh,
                                    g_in_w,g_in_b, g_tr_w,g_tr_b,g_a,
                                    ffn_w,ffn_b,ffn_ow,ffn_ob,
                                    h1a,ssa,sda, dout, s, (s==30)?1:0);
  }
}

// Round 7
// 2520.125 us; speedup vs baseline: 3.0196x; 1.0054x over previous
//
#include <hip/hip_runtime.h>
#include <math.h>

typedef double f64;
#define HDIM 64
#define NNODES 1024
#define NROWS 2048
#define RPB 16      // rows per kAgg block
#define NCH 8       // j-chunks
#define CHJ (NNODES/NCH)   // 128 j per chunk

__device__ __forceinline__ f64 wredsum64(f64 v){
#pragma unroll
  for(int o=32;o>0;o>>=1) v += __shfl_xor(v,o);
  return v;
}

// two-stage score, same op-order as the absmax-0 version
__device__ __forceinline__ void s_twostage64(const f64* __restrict__ ldsrow,
    const float* __restrict__ g_tr_w, const float* __restrict__ g_tr_b,
    const float* __restrict__ g_a, int h, f64& s_src, f64& s_dst){
  f64 t = (f64)g_tr_b[h];
  for(int c=0;c<HDIM;c++) t = fma(ldsrow[c], (f64)g_tr_w[c*HDIM+h], t);
  s_src = wredsum64(t*(f64)g_a[h]);
  s_dst = wredsum64(t*(f64)g_a[HDIM+h]);
}

// parallel f64 transpose of GRU weights: 48 blocks x 256
__global__ void k_pre(const float* __restrict__ w_ih, const float* __restrict__ w_hh,
                      f64* __restrict__ w_ihT, f64* __restrict__ w_hhT){
  int k = blockIdx.x*256 + threadIdx.x;
  if(k >= 192*HDIM) return;
  int row=k>>6, c=k&63;
  w_ihT[c*192+row]=(f64)w_ih[k];
  w_hhT[c*192+row]=(f64)w_hh[k];
}

// initial h1 + scores. 1 wave/row.
__global__ void k1(const float* __restrict__ x, const float* __restrict__ fw,
                   const float* __restrict__ fb,
                   const float* __restrict__ g_in_w, const float* __restrict__ g_in_b,
                   const float* __restrict__ g_tr_w, const float* __restrict__ g_tr_b,
                   const float* __restrict__ g_a,
                   f64* __restrict__ h1, f64* __restrict__ ssrc, f64* __restrict__ sdst){
  __shared__ f64 lx[4*64];
  __shared__ f64 lt[4*64];
  int wave = threadIdx.x >> 6, h = threadIdx.x & 63;
  int r = blockIdx.x*4 + wave;
  int b = r >> 10, n = r & 1023;
  const float* xp = x + ((long)(b*32 + 0)*1024 + n)*6;
  f64 xh = (f64)fb[h];
#pragma unroll
  for(int f=0;f<6;f++) xh += (f64)xp[f]*(f64)fw[f*HDIM+h];
  lx[wave*64+h] = xh;
  __syncthreads();
  f64 a = (f64)g_in_b[h];
  for(int c=0;c<HDIM;c++) a += lx[wave*64+c]*(f64)g_in_w[c*HDIM+h];
  h1[(long)r*HDIM+h] = a;
  lt[wave*64+h] = a;
  __syncthreads();
  f64 s1,s2;
  s_twostage64(lt+wave*64, g_tr_w,g_tr_b,g_a, h, s1,s2);
  if(h==0){ ssrc[r]=s1; sdst[r]=s2; }
}

// Partial attention aggregation. grid = (NROWS/RPB)*NCH = 1024 blocks x 256 thr.
// Block (rg, chunk): rows rg*16..+15, j in [chunk*128, +128).
// Writes pacc[chunk][row][h], pws[chunk][row].
__global__ __launch_bounds__(256) void kAgg(
    const f64* __restrict__ h1_in, const f64* __restrict__ ss_in,
    const f64* __restrict__ sd_in,
    f64* __restrict__ pacc, f64* __restrict__ pws)
{
  __shared__ __align__(16) f64 htile[64*64];  // 32 KB
  __shared__ __align__(16) f64 wbuf[RPB*64];  // 8 KB
  __shared__ f64 lds_m[RPB];
  __shared__ f64 lds_sd[RPB];
  __shared__ f64 red[4];

  const int tid = threadIdx.x, wave = tid>>6, h = tid&63;
  const int chunk = blockIdx.x & (NCH-1);
  const int rg = blockIdx.x >> 3;           // 0..127
  const int batch = rg >> 6;                // 64 rgs * 16 rows = 1024 rows/batch
  const int r0 = rg*RPB;                    // global row base (0..2047)

  const f64* sb = ss_in + (long)batch*NNODES;
  // batch max of s_src
  f64 mx = -1e300;
  for(int j=tid;j<NNODES;j+=256) mx = fmax(mx, sb[j]);
#pragma unroll
  for(int o=32;o>0;o>>=1) mx = fmax(mx, __shfl_xor(mx,o));
  if(h==0) red[wave]=mx;
  __syncthreads();
  f64 maxS = fmax(fmax(red[0],red[1]),fmax(red[2],red[3]));
  if(tid<RPB){
    f64 sd = sd_in[r0+tid];
    lds_sd[tid]=sd;
    f64 v = maxS + sd;
    lds_m[tid] = (v>=0.0)? v : 0.01*v;
  }
  __syncthreads();

  f64 acc0=0.0, acc1=0.0, acc2=0.0, acc3=0.0;   // rows wave*4+0..3
  f64 wsk0=0.0, wsk1=0.0, wsk2=0.0, wsk3=0.0;   // lane-partial ws, rows k*4+wave

  for(int st=0; st<CHJ/64; st++){
    const int j0 = chunk*CHJ + st*64;
    const f64* src = h1_in + ((long)batch*NNODES + j0)*HDIM;
#pragma unroll
    for(int k=0;k<8;k++){
      int idx = tid + k*256;
      ((double2*)htile)[idx] = ((const double2*)src)[idx];
    }
    // W rows: iteration k covers row k*4+wave; lane h holds j0+h's weight.
    // ws accumulated as LANE partials (one butterfly per row at the end).
#pragma unroll
    for(int k=0;k<4;k++){
      int row = k*4 + wave;
      f64 v = sb[j0+h] + lds_sd[row];
      v = (v>=0.0)? v : 0.01*v;
      f64 e = exp(v - lds_m[row]);
      wbuf[row*64+h] = e;
      if(k==0) wsk0+=e; else if(k==1) wsk1+=e; else if(k==2) wsk2+=e; else wsk3+=e;
    }
    __syncthreads();
    const f64* wb = wbuf + (wave*4)*64;
#pragma unroll 4
    for(int jg=0; jg<16; jg++){
      int base = jg*4*64 + h;
      f64 h0 = htile[base], h1v = htile[base+64];
      f64 h2 = htile[base+128], h3 = htile[base+192];
      double2 wa = *(const double2*)(wb + jg*4);
      double2 wa2= *(const double2*)(wb + jg*4 + 2);
      double2 wbv= *(const double2*)(wb + 64 + jg*4);
      double2 wb2= *(const double2*)(wb + 64 + jg*4 + 2);
      double2 wc = *(const double2*)(wb + 128 + jg*4);
      double2 wc2= *(const double2*)(wb + 128 + jg*4 + 2);
      double2 wd = *(const double2*)(wb + 192 + jg*4);
      double2 wd2= *(const double2*)(wb + 192 + jg*4 + 2);
      acc0 = fma(wa.x,h0,acc0);  acc0 = fma(wa.y,h1v,acc0);
      acc0 = fma(wa2.x,h2,acc0); acc0 = fma(wa2.y,h3,acc0);
      acc1 = fma(wbv.x,h0,acc1); acc1 = fma(wbv.y,h1v,acc1);
      acc1 = fma(wb2.x,h2,acc1); acc1 = fma(wb2.y,h3,acc1);
      acc2 = fma(wc.x,h0,acc2);  acc2 = fma(wc.y,h1v,acc2);
      acc2 = fma(wc2.x,h2,acc2); acc2 = fma(wc2.y,h3,acc2);
      acc3 = fma(wd.x,h0,acc3);  acc3 = fma(wd.y,h1v,acc3);
      acc3 = fma(wd2.x,h2,acc3); acc3 = fma(wd2.y,h3,acc3);
    }
    __syncthreads();
  }

  const long pbase = ((long)chunk*NROWS + r0)*HDIM;
  pacc[pbase + (wave*4+0)*HDIM + h] = acc0;
  pacc[pbase + (wave*4+1)*HDIM + h] = acc1;
  pacc[pbase + (wave*4+2)*HDIM + h] = acc2;
  pacc[pbase + (wave*4+3)*HDIM + h] = acc3;
  // one butterfly per row for ws
  f64 w0 = wredsum64(wsk0), w1 = wredsum64(wsk1);
  f64 w2 = wredsum64(wsk2), w3 = wredsum64(wsk3);
  if(h==0){
    f64* pw = pws + (long)chunk*NROWS + r0;
    pw[0*4+wave] = w0; pw[1*4+wave] = w1;
    pw[2*4+wave] = w2; pw[3*4+wave] = w3;
  }
}

// Combine partials -> gat-iter output + residual; then scores. 1 wave/row, grid 512.
__global__ void kFin0(const f64* __restrict__ pacc, const f64* __restrict__ pws,
                      const f64* __restrict__ h1_in,
                      const float* __restrict__ g_tr_w, const float* __restrict__ g_tr_b,
                      const float* __restrict__ g_a,
                      f64* __restrict__ h1_out, f64* __restrict__ ss_out, f64* __restrict__ sd_out){
  __shared__ f64 lt[4*64];
  int wave = threadIdx.x>>6, h = threadIdx.x&63;
  long r = blockIdx.x*4 + wave;
  f64 a = 0.0, w = 0.0;
#pragma unroll
  for(int c=0;c<NCH;c++){
    a += pacc[((long)c*NROWS + r)*HDIM + h];
    w += pws[(long)c*NROWS + r];
  }
  f64 out = a/w + h1_in[r*HDIM+h];
  h1_out[r*HDIM+h] = out;
  lt[wave*64+h] = out;
  __syncthreads();
  f64 s1,s2;
  s_twostage64(lt+wave*64, g_tr_w,g_tr_b,g_a, h, s1,s2);
  if(h==0){ ss_out[r]=s1; sd_out[r]=s2; }
}

// Combine -> gat out; GRU; then next h1+scores or FFN head. 1 wave/row, grid 512.
__global__ void kFin1(const f64* __restrict__ pacc, const f64* __restrict__ pws,
                      const f64* __restrict__ h1_in,
                      const float* __restrict__ x, const float* __restrict__ fw,
                      const float* __restrict__ fb,
                      const f64* __restrict__ w_ihT, const f64* __restrict__ w_hhT,
                      const float* __restrict__ b_ih, const float* __restrict__ b_hh,
                      const float* __restrict__ g_in_w, const float* __restrict__ g_in_b,
                      const float* __restrict__ g_tr_w, const float* __restrict__ g_tr_b,
                      const float* __restrict__ g_a,
                      const float* __restrict__ ffn_w, const float* __restrict__ ffn_b,
                      const float* __restrict__ ffn_ow, const float* __restrict__ ffn_ob,
                      f64* __restrict__ h1_out, f64* __restrict__ ss_out, f64* __restrict__ sd_out,
                      float* __restrict__ out, int step, int is_final){
  __shared__ f64 lo[4*64];
  __shared__ f64 lx[4*64];
  __shared__ f64 lh[4*64];
  int wave = threadIdx.x>>6, h = threadIdx.x&63;
  long r = blockIdx.x*4 + wave;
  int batch = (int)(r>>10), n = (int)(r&1023);
  f64 a = 0.0, w = 0.0;
#pragma unroll
  for(int c=0;c<NCH;c++){
    a += pacc[((long)c*NROWS + r)*HDIM + h];
    w += pws[(long)c*NROWS + r];
  }
  f64 gato = a/w + h1_in[r*HDIM+h];
  lo[wave*64+h] = gato;
  const bool hasxi = (step>0);
  if(hasxi){
    const float* xp = x + ((long)(batch*32 + step)*1024 + n)*6;
    f64 xi = (f64)fb[h];
#pragma unroll
    for(int f=0;f<6;f++) xi += (f64)xp[f]*(f64)fw[f*HDIM+h];
    lx[wave*64+h] = xi;
  }
  __syncthreads();
  f64 gi0=(f64)b_ih[h], gi1=(f64)b_ih[64+h], gi2=(f64)b_ih[128+h];
  f64 gh0=(f64)b_hh[h], gh1=(f64)b_hh[64+h], gh2=(f64)b_hh[128+h];
  for(int c=0;c<HDIM;c++){
    f64 o = lo[wave*64+c];
    f64 in = hasxi ? lx[wave*64+c] : o;
    gi0 += in*w_ihT[c*192+h]; gi1 += in*w_ihT[c*192+64+h]; gi2 += in*w_ihT[c*192+128+h];
    if(hasxi){
      gh0 += o*w_hhT[c*192+h]; gh1 += o*w_hhT[c*192+64+h]; gh2 += o*w_hhT[c*192+128+h];
    }
  }
  f64 rr = 1.0/(1.0+exp(-(gi0+gh0)));
  f64 zz = 1.0/(1.0+exp(-(gi1+gh1)));
  f64 nn = tanh(gi2 + rr*gh2);
  f64 hn = hasxi ? ((1.0-zz)*nn + zz*gato) : (1.0-zz)*nn;
  lh[wave*64+h] = hn;
  __syncthreads();
  if(!is_final){
    f64 a1 = (f64)g_in_b[h];
    for(int c=0;c<HDIM;c++) a1 += lh[wave*64+c]*(f64)g_in_w[c*HDIM+h];
    h1_out[r*HDIM+h] = a1;
    lx[wave*64+h] = a1;
    __syncthreads();
    f64 s1,s2;
    s_twostage64(lx+wave*64, g_tr_w,g_tr_b,g_a, h, s1,s2);
    if(h==0){ ss_out[r]=s1; sd_out[r]=s2; }
  } else {
    f64 hid = (f64)ffn_b[h];
    for(int c=0;c<HDIM;c++) hid += lh[wave*64+c]*(f64)ffn_w[c*HDIM+h];
    hid = (hid>=0.0)? hid : 0.01*hid;
    f64 o2 = wredsum64(hid*(f64)ffn_ow[h]);
    if(h==0) out[r] = (float)(o2 + (f64)ffn_ob[0]);
  }
}

extern "C" void kernel_launch(void* const* d_in, const int* in_sizes, int n_in,
                              void* d_out, int out_size, void* d_ws, size_t ws_size,
                              hipStream_t stream){
  const float* x      = (const float*)d_in[0];
  const float* fc_in_w= (const float*)d_in[1];
  const float* fc_in_b= (const float*)d_in[2];
  const float* g_in_w = (const float*)d_in[3];
  const float* g_in_b = (const float*)d_in[4];
  const float* g_tr_w = (const float*)d_in[5];
  const float* g_tr_b = (const float*)d_in[6];
  const float* g_a    = (const float*)d_in[7];
  const float* w_ih   = (const float*)d_in[8];
  const float* w_hh   = (const float*)d_in[9];
  const float* b_ih   = (const float*)d_in[10];
  const float* b_hh   = (const float*)d_in[11];
  const float* ffn_w  = (const float*)d_in[12];
  const float* ffn_b  = (const float*)d_in[13];
  const float* ffn_ow = (const float*)d_in[14];
  const float* ffn_ob = (const float*)d_in[15];

  // workspace (f64): h1 2*131072; scores 4*2048; wT 2*12288; pacc 8*131072; pws 8*2048  ~11.5MB (ws=256MB)
  f64* h1a   = (f64*)d_ws;
  f64* h1b   = h1a + (long)NROWS*HDIM;
  f64* ssa   = h1b + (long)NROWS*HDIM;
  f64* sda   = ssa + NROWS;
  f64* ssb   = sda + NROWS;
  f64* sdb   = ssb + NROWS;
  f64* w_ihT = sdb + NROWS;
  f64* w_hhT = w_ihT + 192*HDIM;
  f64* pacc  = w_hhT + 192*HDIM;
  f64* pws   = pacc + (long)NCH*NROWS*HDIM;

  float* dout = (float*)d_out;

  k_pre<<<48,256,0,stream>>>(w_ih,w_hh,w_ihT,w_hhT);
  k1<<<NROWS/4,256,0,stream>>>(x, fc_in_w, fc_in_b, g_in_w,g_in_b,
                               g_tr_w,g_tr_b,g_a, h1a,ssa,sda);

  for(int s=0;s<31;s++){
    kAgg<<<(NROWS/RPB)*NCH,256,0,stream>>>(h1a,ssa,sda, pacc,pws);
    kFin0<<<NROWS/4,256,0,stream>>>(pacc,pws,h1a, g_tr_w,g_tr_b,g_a, h1b,ssb,sdb);
    kAgg<<<(NROWS/RPB)*NCH,256,0,stream>>>(h1b,ssb,sdb, pacc,pws);
    kFin1<<<NROWS/4,256,0,stream>>>(pacc,pws,h1b,
                                    x,fc_in_w,fc_in_b,
                                    w_ihT,w_hhT,b_ih,b_hh,
                                    g_in_w,g_in_b, g_tr_w,g_tr_b,g_a,
                                    ffn_w,ffn_b,ffn_ow,ffn_ob,
                                    h1a,ssa,sda, dout, s, (s==30)?1:0);
  }
}